// Round 4
// baseline (152.635 us; speedup 1.0000x reference)
//
#include <hip/hip_runtime.h>
#include <math.h>

#define K_CNT 8
#define IMG_H 1024
#define IMG_W 1024
#define SW 608            // scratch row stride (floats); max region w = 606
#define SH 272            // scratch rows; max region h = 270
#define SLOT (SW * SH)    // floats per region slot
#define TROWS 476         // LDS tmp row stride: 476 % 32 == 28 -> uniform bank tiling for b128

struct RegionMeta {
  int ys, ye, xs, xe;
  int skip, r, L;
  float dxp, dyp;
  int pad0, pad1, pad2;
};

// One block (64 threads) per (i,k) region: compute rect, offsets, and the
// 1D kernel gn3 = gn*gn*gn (separable equivalent of 3x 2D gauss conv).
__global__ void meta_kernel(const float* __restrict__ sigp,
                            const float* __restrict__ tnhp,
                            const int* __restrict__ ta,
                            float* __restrict__ g3out,
                            RegionMeta* __restrict__ meta)
{
  int bid = blockIdx.x;          // i*K + k
  int k = bid % K_CNT;
  int lane = threadIdx.x;

  __shared__ int bx[8];
  if (lane < 8) bx[lane] = ta[bid * 8 + lane];
  __syncthreads();
  int ys0 = min(min(bx[1], bx[3]), min(bx[5], bx[7]));
  int ye0 = max(max(bx[1], bx[3]), max(bx[5], bx[7]));
  int xs0 = min(min(bx[0], bx[2]), min(bx[4], bx[6]));
  int xe0 = max(max(bx[0], bx[2]), max(bx[4], bx[6]));
  int h = ye0 - ys0, w = xe0 - xs0;

  // NOTE: reference indexes flattened params by k only (batch-0 params for all i)
  float sig1 = sigp[k * 2 + 1];
  float t0 = tnhp[k * 2 + 0], t1 = tnhp[k * 2 + 1];

  float blur = ((sig1 + 1e-5f) * (float)h) * 0.5f;      // f32 like jnp
  double kfac = 0.75 * sqrt(2.0 * M_PI);                // exact Python f64 path
  int ks = (int)floor((double)blur * kfac + 0.5);
  if (ks < 2) ks = 2;
  if ((ks & 1) == 0) ks += 1;
  int r = ks >> 1, P = r * 3, L = 3 * ks - 2;
  float dxp = (t0 * (float)h) * 0.2f;
  float dyp = (t1 * (float)h) * 0.2f;
  double eh = (double)P + fabs((double)dyp);
  double ew = (double)P + fabs((double)dxp);
  int ys = (int)fmax(fmin((double)ys0 - eh, (double)IMG_H), 0.0);
  int ye = (int)fmax(fmin((double)ye0 + eh, (double)IMG_H), 0.0);
  int xs = (int)fmax(fmin((double)xs0 - ew, (double)IMG_W), 0.0);
  int xe = (int)fmax(fmin((double)xe0 + ew, (double)IMG_W), 0.0);
  int skip = (h < 5 || w < 5) ? 1 : 0;

  if (lane == 0) {
    RegionMeta m;
    m.ys = ys; m.ye = ye; m.xs = xs; m.xe = xe;
    m.skip = skip; m.r = r; m.L = L;
    m.dxp = dxp; m.dyp = dyp;
    m.pad0 = m.pad1 = m.pad2 = 0;
    meta[bid] = m;
  }

  // 1D gaussian (unnormalized prefactor cancels in normalization)
  float mean = 0.5f * (float)(ks - 1);
  float inv = 1.0f / (2.0f * blur);
  float gx = 0.f;
  if (lane < ks) { float d = ((float)lane - mean) * inv; gx = expf(-(d * d)); }
  float S = gx;
  #pragma unroll
  for (int off = 32; off > 0; off >>= 1) S += __shfl_xor(S, off);
  __shared__ float gn[64];
  gn[lane] = (lane < ks) ? gx / S : 0.f;
  __syncthreads();

  __shared__ float g2[128];
  for (int a = lane; a < 2 * ks - 1; a += 64) {
    int blo = max(0, a - ks + 1), bhi = min(a, ks - 1);
    float s = 0.f;
    for (int b = blo; b <= bhi; ++b) s += gn[b] * gn[a - b];
    g2[a] = s;
  }
  __syncthreads();

  float* g3 = g3out + (size_t)bid * 256;
  for (int a = lane; a < 256; a += 64) {
    float s = 0.f;
    if (a < L) {
      int blo = max(0, a - (2 * ks - 2)), bhi = min(a, ks - 1);
      for (int b = blo; b <= bhi; ++b) s += gn[b] * g2[a - b];
    }
    g3[a] = s;   // zero-padded beyond L (rolling loops rely on this)
  }
}

// Fused h+v separable conv for one (region, 16-wide x-strip).
// kk >= 0: fallback mode (region = z*K+kk, slot z in 0..3). kk == -1: region = z, slot z.
__global__ __launch_bounds__(320) void blur_fused(const float* __restrict__ alpha,
                                                  const RegionMeta* __restrict__ meta,
                                                  const float* __restrict__ g3all,
                                                  float* __restrict__ blurred, int kk)
{
  int z = blockIdx.y;
  int reg = (kk >= 0) ? z * K_CNT + kk : z;
  int i   = (kk >= 0) ? z : z / K_CNT;
  RegionMeta m = meta[reg];
  if (m.skip) return;
  int ch = m.ye - m.ys, cw = m.xe - m.xs;
  if (ch > SH) ch = SH;
  if (cw > SW) cw = SW;
  int x0 = blockIdx.x * 16;
  if (x0 >= cw) return;

  int P = m.r * 3;
  int Lpad32 = (m.L + 31) & ~31;   // <= 224
  int Lpad16 = (m.L + 15) & ~15;   // <= 192

  __shared__ float g3s[256];
  __shared__ float tmp[16][TROWS]; // tmp[x][t] = h-out row (t-P) of column x0+x; zero pads
  int tid = threadIdx.x;
  for (int a = tid; a < 256; a += 320) g3s[a] = g3all[(size_t)reg * 256 + a];
  {
    float* tz = &tmp[0][0];
    for (int a = tid; a < 16 * TROWS; a += 320) tz[a] = 0.f;
  }
  __syncthreads();

  // ---- h-conv: one thread per image row; 16 x-outputs via 32-reg circular window
  int y = tid;
  if (y < ch) {
    const float* row = alpha + ((size_t)i * IMG_H + (m.ys + y)) * IMG_W + m.xs;
    int base = x0 - P;             // in_pad[t] = row[base + t] guarded to [0,cw)
    float w[32], acc[16];
    #pragma unroll
    for (int q = 0; q < 32; ++q) { int c = base + q; w[q] = (c >= 0 && c < cw) ? row[c] : 0.f; }
    #pragma unroll
    for (int x = 0; x < 16; ++x) acc[x] = 0.f;
    for (int jj = 0; jj < Lpad32; jj += 32) {
      #pragma unroll
      for (int u = 0; u < 16; ++u) {
        float g = g3s[jj + u];
        #pragma unroll
        for (int x = 0; x < 16; ++x) acc[x] += g * w[(u + x) & 31];
      }
      #pragma unroll
      for (int s = 0; s < 16; ++s) { int c = base + jj + 32 + s; w[s] = (c >= 0 && c < cw) ? row[c] : 0.f; }
      #pragma unroll
      for (int u = 0; u < 16; ++u) {
        float g = g3s[jj + 16 + u];
        #pragma unroll
        for (int x = 0; x < 16; ++x) acc[x] += g * w[(16 + u + x) & 31];
      }
      #pragma unroll
      for (int s = 0; s < 16; ++s) { int c = base + jj + 48 + s; w[16 + s] = (c >= 0 && c < cw) ? row[c] : 0.f; }
    }
    #pragma unroll
    for (int x = 0; x < 16; ++x) tmp[x][P + y] = acc[x];
  }
  __syncthreads();

  // ---- v-conv: thread = (x, y-group); 8 consecutive y via 16-reg circular window
  int xl = tid & 15, yg = tid >> 4;   // yg in 0..19
  #pragma unroll
  for (int pass = 0; pass < 2; ++pass) {
    int y0 = (yg + pass * 20) * 8;
    if (y0 >= ch) continue;
    float w[16], acc[8];
    #pragma unroll
    for (int q = 0; q < 16; ++q) w[q] = tmp[xl][y0 + q];
    #pragma unroll
    for (int v = 0; v < 8; ++v) acc[v] = 0.f;
    for (int jj = 0; jj < Lpad16; jj += 16) {
      #define VPH(PH)                                                            \
      {                                                                          \
        _Pragma("unroll")                                                        \
        for (int u = 0; u < 4; ++u) {                                            \
          float g = g3s[jj + (PH) + u];                                          \
          _Pragma("unroll")                                                      \
          for (int v = 0; v < 8; ++v) acc[v] += g * w[((PH) + u + v) & 15];      \
        }                                                                        \
        _Pragma("unroll")                                                        \
        for (int s = 0; s < 4; ++s)                                              \
          w[((PH) + s) & 15] = tmp[xl][y0 + jj + (PH) + 16 + s];                 \
      }
      VPH(0) VPH(4) VPH(8) VPH(12)
      #undef VPH
    }
    if (x0 + xl < cw) {
      float* op = blurred + (size_t)z * SLOT + (size_t)y0 * SW + x0 + xl;
      #pragma unroll
      for (int v = 0; v < 8; ++v)
        if (y0 + v < ch) op[(size_t)v * SW] = acc[v];
    }
  }
}

// Parallel path: resolve ascending-k overwrite semantics by descending-k scan.
// sg = shifted value of max covering k; sl = k+1 of max covering k with v>0.
__global__ void composite_kernel(const RegionMeta* __restrict__ meta,
                                 const float* __restrict__ blurred,
                                 float* __restrict__ sg, float* __restrict__ sl)
{
  __shared__ RegionMeta ms[32];
  {
    const int* src = (const int*)meta;
    int* dst = (int*)ms;
    for (int a = threadIdx.x; a < 32 * (int)(sizeof(RegionMeta) / 4); a += 256) dst[a] = src[a];
  }
  __syncthreads();
  int idx = blockIdx.x * 256 + threadIdx.x;
  int x = idx & (IMG_W - 1);
  int y = (idx >> 10) & (IMG_H - 1);
  int i = idx >> 20;
  float sgv = 0.f, slv = 0.f;
  bool got = false;
  for (int k = K_CNT - 1; k >= 0; --k) {
    const RegionMeta& m = ms[i * K_CNT + k];
    if (m.skip) continue;
    int ch = m.ye - m.ys, cw = m.xe - m.xs;
    if (ch > SH) ch = SH;
    if (cw > SW) cw = SW;
    int ly = y - m.ys, lx = x - m.xs;
    if (ly < 0 || ly >= ch || lx < 0 || lx >= cw) continue;
    float sy = (float)ly - m.dyp;
    float sx = (float)lx - m.dxp;
    float x0f = floorf(sx), y0f = floorf(sy);
    float wx = sx - x0f, wy = sy - y0f;
    int x0 = (int)x0f, y0 = (int)y0f;
    const float* bl = blurred + (size_t)(i * K_CNT + k) * SLOT;
    float v00 = (y0 >= 0 && y0 < ch && x0 >= 0 && x0 < cw) ? bl[y0 * SW + x0] : 0.f;
    float v01 = (y0 >= 0 && y0 < ch && x0 + 1 >= 0 && x0 + 1 < cw) ? bl[y0 * SW + x0 + 1] : 0.f;
    float v10 = (y0 + 1 >= 0 && y0 + 1 < ch && x0 >= 0 && x0 < cw) ? bl[(y0 + 1) * SW + x0] : 0.f;
    float v11 = (y0 + 1 >= 0 && y0 + 1 < ch && x0 + 1 >= 0 && x0 + 1 < cw) ? bl[(y0 + 1) * SW + x0 + 1] : 0.f;
    float v = (1.f - wy) * ((1.f - wx) * v00 + wx * v01) + wy * ((1.f - wx) * v10 + wx * v11);
    if (!got) { sgv = v; got = true; }
    if (v > 0.f) { slv = (float)(k + 1); break; }
  }
  sg[idx] = sgv;
  sl[idx] = slv;
}

// Fallback-path bilinear translate + write (ascending-k launches give overwrite semantics)
__global__ void shift_kernel(const RegionMeta* __restrict__ meta,
                             const float* __restrict__ blurred,
                             float* __restrict__ sg, float* __restrict__ sl, int k)
{
  int i = blockIdx.y;
  RegionMeta m = meta[i * K_CNT + k];
  if (m.skip) return;
  int ch = m.ye - m.ys, cw = m.xe - m.xs;
  if (ch > SH) ch = SH;
  if (cw > SW) cw = SW;
  int idx = blockIdx.x * 256 + threadIdx.x;
  int x = idx % SW, y = idx / SW;
  if (y >= ch || x >= cw) return;

  float sy = (float)y - m.dyp;
  float sx = (float)x - m.dxp;
  float x0f = floorf(sx), y0f = floorf(sy);
  float wx = sx - x0f, wy = sy - y0f;
  int x0 = (int)x0f, y0 = (int)y0f;
  const float* bl = blurred + (size_t)i * SLOT;

  float v00 = (y0 >= 0 && y0 < ch && x0 >= 0 && x0 < cw) ? bl[y0 * SW + x0] : 0.f;
  float v01 = (y0 >= 0 && y0 < ch && x0 + 1 >= 0 && x0 + 1 < cw) ? bl[y0 * SW + x0 + 1] : 0.f;
  float v10 = (y0 + 1 >= 0 && y0 + 1 < ch && x0 >= 0 && x0 < cw) ? bl[(y0 + 1) * SW + x0] : 0.f;
  float v11 = (y0 + 1 >= 0 && y0 + 1 < ch && x0 + 1 >= 0 && x0 + 1 < cw) ? bl[(y0 + 1) * SW + x0 + 1] : 0.f;

  float v = (1.f - wy) * ((1.f - wx) * v00 + wx * v01) + wy * ((1.f - wx) * v10 + wx * v11);

  size_t o = ((size_t)i * IMG_H + (m.ys + y)) * IMG_W + (m.xs + x);
  sg[o] = v;
  if (v > 0.f) sl[o] = (float)(k + 1);
}

extern "C" void kernel_launch(void* const* d_in, const int* in_sizes, int n_in,
                              void* d_out, int out_size, void* d_ws, size_t ws_size,
                              hipStream_t stream) {
  const float* alpha = (const float*)d_in[0];
  // d_in[1] (font_size_pred) is unused by the reference
  const float* sigp = (const float*)d_in[2];
  const float* tnhp = (const float*)d_in[3];
  const int* ta = (const int*)d_in[4];
  float* out = (float*)d_out;

  char* ws = (char*)d_ws;
  RegionMeta* meta = (RegionMeta*)ws;
  float* g3 = (float*)(ws + 4096);

  float* sg = out;
  float* sl = out + (size_t)4 * IMG_H * IMG_W;

  const size_t slotBytes = (size_t)SLOT * 4;
  const size_t needPar = 65536 + 32 * slotBytes;   // ~21.2 MB
  const int nStrips = (SW + 15) / 16;              // 38

  meta_kernel<<<32, 64, 0, stream>>>(sigp, tnhp, ta, g3, meta);

  if (ws_size >= needPar) {
    // fully parallel across all 32 regions; ordering resolved in composite
    float* blurred = (float*)(ws + 65536);
    blur_fused<<<dim3(nStrips, 32), 320, 0, stream>>>(alpha, meta, g3, blurred, -1);
    composite_kernel<<<(4 * IMG_H * IMG_W) / 256, 256, 0, stream>>>(meta, blurred, sg, sl);
  } else {
    // fallback: sequential over k (4 regions in parallel), explicit write ordering
    float* blurred = (float*)(ws + 65536);
    hipMemsetAsync(d_out, 0, (size_t)out_size * sizeof(float), stream);
    const int blocksPerRegion = (SH * SW) / 256;
    for (int k = 0; k < K_CNT; ++k) {
      blur_fused<<<dim3(nStrips, 4), 320, 0, stream>>>(alpha, meta, g3, blurred, k);
      shift_kernel<<<dim3(blocksPerRegion, 4), 256, 0, stream>>>(meta, blurred, sg, sl, k);
    }
  }
}

// Round 5
// 94.687 us; speedup vs baseline: 1.6120x; 1.6120x over previous
//
#include <hip/hip_runtime.h>
#include <math.h>

#define K_CNT 8
#define IMG_H 1024
#define IMG_W 1024
#define SW 608            // scratch row stride (floats); max region w = 606
#define SH 272            // scratch rows; max region h = 270
#define SLOT (SW * SH)    // floats per region slot
#define HROWS 5           // rows per hpass block

struct RegionMeta {
  int ys, ye, xs, xe;
  int skip, r, L;
  float dxp, dyp;
  int pad0, pad1, pad2;
};

// One block (64 threads) per (i,k) region: compute rect, offsets, and the
// 1D kernel gn3 = gn*gn*gn (separable equivalent of 3x 2D gauss conv).
__global__ void meta_kernel(const float* __restrict__ sigp,
                            const float* __restrict__ tnhp,
                            const int* __restrict__ ta,
                            float* __restrict__ g3out,
                            RegionMeta* __restrict__ meta)
{
  int bid = blockIdx.x;          // i*K + k
  int k = bid % K_CNT;
  int lane = threadIdx.x;

  __shared__ int bx[8];
  if (lane < 8) bx[lane] = ta[bid * 8 + lane];
  __syncthreads();
  int ys0 = min(min(bx[1], bx[3]), min(bx[5], bx[7]));
  int ye0 = max(max(bx[1], bx[3]), max(bx[5], bx[7]));
  int xs0 = min(min(bx[0], bx[2]), min(bx[4], bx[6]));
  int xe0 = max(max(bx[0], bx[2]), max(bx[4], bx[6]));
  int h = ye0 - ys0, w = xe0 - xs0;

  // NOTE: reference indexes flattened params by k only (batch-0 params for all i)
  float sig1 = sigp[k * 2 + 1];
  float t0 = tnhp[k * 2 + 0], t1 = tnhp[k * 2 + 1];

  float blur = ((sig1 + 1e-5f) * (float)h) * 0.5f;      // f32 like jnp
  double kfac = 0.75 * sqrt(2.0 * M_PI);                // exact Python f64 path
  int ks = (int)floor((double)blur * kfac + 0.5);
  if (ks < 2) ks = 2;
  if ((ks & 1) == 0) ks += 1;
  int r = ks >> 1, P = r * 3, L = 3 * ks - 2;
  float dxp = (t0 * (float)h) * 0.2f;
  float dyp = (t1 * (float)h) * 0.2f;
  double eh = (double)P + fabs((double)dyp);
  double ew = (double)P + fabs((double)dxp);
  int ys = (int)fmax(fmin((double)ys0 - eh, (double)IMG_H), 0.0);
  int ye = (int)fmax(fmin((double)ye0 + eh, (double)IMG_H), 0.0);
  int xs = (int)fmax(fmin((double)xs0 - ew, (double)IMG_W), 0.0);
  int xe = (int)fmax(fmin((double)xe0 + ew, (double)IMG_W), 0.0);
  int skip = (h < 5 || w < 5) ? 1 : 0;

  if (lane == 0) {
    RegionMeta m;
    m.ys = ys; m.ye = ye; m.xs = xs; m.xe = xe;
    m.skip = skip; m.r = r; m.L = L;
    m.dxp = dxp; m.dyp = dyp;
    m.pad0 = m.pad1 = m.pad2 = 0;
    meta[bid] = m;
  }

  // 1D gaussian (unnormalized prefactor cancels in normalization)
  float mean = 0.5f * (float)(ks - 1);
  float inv = 1.0f / (2.0f * blur);
  float gx = 0.f;
  if (lane < ks) { float d = ((float)lane - mean) * inv; gx = expf(-(d * d)); }
  float S = gx;
  #pragma unroll
  for (int off = 32; off > 0; off >>= 1) S += __shfl_xor(S, off);
  __shared__ float gn[64];
  gn[lane] = (lane < ks) ? gx / S : 0.f;
  __syncthreads();

  __shared__ float g2[128];
  for (int a = lane; a < 2 * ks - 1; a += 64) {
    int blo = max(0, a - ks + 1), bhi = min(a, ks - 1);
    float s = 0.f;
    for (int b = blo; b <= bhi; ++b) s += gn[b] * gn[a - b];
    g2[a] = s;
  }
  __syncthreads();

  float* g3 = g3out + (size_t)bid * 256;
  for (int a = lane; a < 256; a += 64) {
    float s = 0.f;
    if (a < L) {
      int blo = max(0, a - (2 * ks - 2)), bhi = min(a, ks - 1);
      for (int b = blo; b <= bhi; ++b) s += gn[b] * g2[a - b];
    }
    g3[a] = s;   // zero-padded beyond L (rolling loops rely on this)
  }
}

// Horizontal pass: block = (region, group of HROWS rows). Row staged in LDS;
// each thread computes 16 consecutive x-outputs via a 32-float register ring.
// kk >= 0: fallback (region = by*K+kk). kk == -1: region = blockIdx.y.
__global__ __launch_bounds__(192) void hpass_kernel(const float* __restrict__ alpha,
                             const RegionMeta* __restrict__ meta,
                             const float* __restrict__ g3all,
                             float* __restrict__ tmpH, int kk)
{
  int z = blockIdx.y;
  int reg = (kk >= 0) ? z * K_CNT + kk : z;
  int i   = (kk >= 0) ? z : z / K_CNT;
  RegionMeta m = meta[reg];
  if (m.skip) return;
  int ch = m.ye - m.ys, cw = m.xe - m.xs;
  if (ch > SH) ch = SH;
  if (cw > SW) cw = SW;
  int ybase = blockIdx.x * HROWS;
  if (ybase >= ch) return;
  int P = m.r * 3;
  int Lp = (m.L + 7) & ~7;           // <= 184

  __shared__ float g3s[256];
  __shared__ float srow[HROWS][832]; // srow[r][e] = row[e - P], zero outside [0,cw)
  int tid = threadIdx.x;
  for (int a = tid; a < 256; a += 192) g3s[a] = g3all[(size_t)reg * 256 + a];
  int nrows = min(HROWS, ch - ybase);
  for (int s = tid; s < nrows * 208; s += 192) {
    int r = s / 208;
    int e = (s - r * 208) * 4;
    const float* row = alpha + ((size_t)i * IMG_H + (m.ys + ybase + r)) * IMG_W + m.xs;
    float4 v;
    float* vp = (float*)&v;
    #pragma unroll
    for (int u = 0; u < 4; ++u) {
      int c = e + u - P;
      vp[u] = (c >= 0 && c < cw) ? row[c] : 0.f;
    }
    *(float4*)(&srow[r][e]) = v;
  }
  __syncthreads();

  int r = tid / 38, c = tid - (tid / 38) * 38;   // 5 rows x 38 chunks (190 active)
  int y = ybase + r;
  int x0 = 16 * c;
  if (r >= HROWS || y >= ch || x0 >= cw) return;
  const float* sp = &srow[r][x0];

  float w[32];
  #pragma unroll
  for (int q = 0; q < 8; ++q) *(float4*)(&w[4 * q]) = *(const float4*)(sp + 4 * q);
  float acc[16];
  #pragma unroll
  for (int t = 0; t < 16; ++t) acc[t] = 0.f;

  for (int jj = 0; jj < Lp; jj += 32) {
    #define HPH(PH)                                                         \
    if (jj + (PH) < Lp) {                                                   \
      float ga[8];                                                          \
      *(float4*)(ga)     = *(const float4*)(&g3s[jj + (PH)]);               \
      *(float4*)(ga + 4) = *(const float4*)(&g3s[jj + (PH) + 4]);           \
      _Pragma("unroll")                                                     \
      for (int u = 0; u < 8; ++u) {                                         \
        float g = ga[u];                                                    \
        _Pragma("unroll")                                                   \
        for (int t = 0; t < 16; ++t) acc[t] += g * w[((PH) + u + t) & 31];  \
      }                                                                     \
      float4 p0 = *(const float4*)(sp + jj + (PH) + 32);                    \
      float4 p1 = *(const float4*)(sp + jj + (PH) + 36);                    \
      *(float4*)(&w[(PH)])     = p0;                                        \
      *(float4*)(&w[(PH) + 4]) = p1;                                        \
    }
    HPH(0) HPH(8) HPH(16) HPH(24)
    #undef HPH
  }

  float* op = tmpH + (size_t)z * SLOT + (size_t)y * SW + x0;
  #pragma unroll
  for (int q = 0; q < 4; ++q)
    *(float4*)(op + 4 * q) = *(float4*)(&acc[4 * q]);
}

// Vertical pass: 16 consecutive y-outputs per thread via 32-float register
// ring on the global column; guard-free loads except at y-boundaries.
__global__ __launch_bounds__(256) void vpass_kernel(const RegionMeta* __restrict__ meta,
                             const float* __restrict__ g3all,
                             const float* __restrict__ tmpH,
                             float* __restrict__ blurred, int kk)
{
  int z = blockIdx.z;
  int reg = (kk >= 0) ? z * K_CNT + kk : z;
  RegionMeta m = meta[reg];
  __shared__ float g3s[256];
  g3s[threadIdx.x] = g3all[(size_t)reg * 256 + threadIdx.x];
  __syncthreads();
  if (m.skip) return;
  int ch = m.ye - m.ys, cw = m.xe - m.xs;
  if (ch > SH) ch = SH;
  if (cw > SW) cw = SW;
  int x = blockIdx.x * 256 + threadIdx.x;
  if (x >= cw) return;
  int y0 = blockIdx.y * 16;
  if (y0 >= ch) return;
  int P = m.r * 3;
  int Lp = (m.L + 7) & ~7;
  const float* col = tmpH + (size_t)z * SLOT + x;
  int base = y0 - P;

  float w[32];
  if (base >= 0 && base + 31 < ch) {
    #pragma unroll
    for (int s = 0; s < 32; ++s) w[s] = col[(size_t)(base + s) * SW];
  } else {
    #pragma unroll
    for (int s = 0; s < 32; ++s) {
      int rr = base + s;
      w[s] = (rr >= 0 && rr < ch) ? col[(size_t)rr * SW] : 0.f;
    }
  }
  float acc[16];
  #pragma unroll
  for (int v = 0; v < 16; ++v) acc[v] = 0.f;

  for (int jj = 0; jj < Lp; jj += 32) {
    #define VPH(PH)                                                          \
    if (jj + (PH) < Lp) {                                                    \
      float ga[8];                                                           \
      *(float4*)(ga)     = *(const float4*)(&g3s[jj + (PH)]);                \
      *(float4*)(ga + 4) = *(const float4*)(&g3s[jj + (PH) + 4]);            \
      _Pragma("unroll")                                                      \
      for (int u = 0; u < 8; ++u) {                                          \
        float g = ga[u];                                                     \
        _Pragma("unroll")                                                    \
        for (int v = 0; v < 16; ++v) acc[v] += g * w[((PH) + u + v) & 31];   \
      }                                                                      \
      int rb = base + jj + (PH) + 32;                                        \
      if (rb >= 0 && rb + 7 < ch) {                                          \
        _Pragma("unroll")                                                    \
        for (int q = 0; q < 8; ++q) w[((PH) + q) & 31] = col[(size_t)(rb + q) * SW]; \
      } else {                                                               \
        _Pragma("unroll")                                                    \
        for (int q = 0; q < 8; ++q) {                                        \
          int rr = rb + q;                                                   \
          w[((PH) + q) & 31] = (rr >= 0 && rr < ch) ? col[(size_t)rr * SW] : 0.f; \
        }                                                                    \
      }                                                                      \
    }
    VPH(0) VPH(8) VPH(16) VPH(24)
    #undef VPH
  }

  float* op = blurred + (size_t)z * SLOT + (size_t)y0 * SW + x;
  #pragma unroll
  for (int v = 0; v < 16; ++v)
    if (y0 + v < ch) op[(size_t)v * SW] = acc[v];
}

// Parallel path: resolve ascending-k overwrite semantics by descending-k scan.
// sg = shifted value of max covering k; sl = k+1 of max covering k with v>0.
__global__ void composite_kernel(const RegionMeta* __restrict__ meta,
                                 const float* __restrict__ blurred,
                                 float* __restrict__ sg, float* __restrict__ sl)
{
  __shared__ RegionMeta ms[32];
  {
    const int* src = (const int*)meta;
    int* dst = (int*)ms;
    for (int a = threadIdx.x; a < 32 * (int)(sizeof(RegionMeta) / 4); a += 256) dst[a] = src[a];
  }
  __syncthreads();
  int idx = blockIdx.x * 256 + threadIdx.x;
  int x = idx & (IMG_W - 1);
  int y = (idx >> 10) & (IMG_H - 1);
  int i = idx >> 20;
  float sgv = 0.f, slv = 0.f;
  bool got = false;
  for (int k = K_CNT - 1; k >= 0; --k) {
    const RegionMeta& m = ms[i * K_CNT + k];
    if (m.skip) continue;
    int ch = m.ye - m.ys, cw = m.xe - m.xs;
    if (ch > SH) ch = SH;
    if (cw > SW) cw = SW;
    int ly = y - m.ys, lx = x - m.xs;
    if (ly < 0 || ly >= ch || lx < 0 || lx >= cw) continue;
    float sy = (float)ly - m.dyp;
    float sx = (float)lx - m.dxp;
    float x0f = floorf(sx), y0f = floorf(sy);
    float wx = sx - x0f, wy = sy - y0f;
    int x0 = (int)x0f, y0 = (int)y0f;
    const float* bl = blurred + (size_t)(i * K_CNT + k) * SLOT;
    float v00 = (y0 >= 0 && y0 < ch && x0 >= 0 && x0 < cw) ? bl[y0 * SW + x0] : 0.f;
    float v01 = (y0 >= 0 && y0 < ch && x0 + 1 >= 0 && x0 + 1 < cw) ? bl[y0 * SW + x0 + 1] : 0.f;
    float v10 = (y0 + 1 >= 0 && y0 + 1 < ch && x0 >= 0 && x0 < cw) ? bl[(y0 + 1) * SW + x0] : 0.f;
    float v11 = (y0 + 1 >= 0 && y0 + 1 < ch && x0 + 1 >= 0 && x0 + 1 < cw) ? bl[(y0 + 1) * SW + x0 + 1] : 0.f;
    float v = (1.f - wy) * ((1.f - wx) * v00 + wx * v01) + wy * ((1.f - wx) * v10 + wx * v11);
    if (!got) { sgv = v; got = true; }
    if (v > 0.f) { slv = (float)(k + 1); break; }
  }
  sg[idx] = sgv;
  sl[idx] = slv;
}

// Fallback-path bilinear translate + write (ascending-k launches give overwrite semantics)
__global__ void shift_kernel(const RegionMeta* __restrict__ meta,
                             const float* __restrict__ blurred,
                             float* __restrict__ sg, float* __restrict__ sl, int k)
{
  int i = blockIdx.y;
  RegionMeta m = meta[i * K_CNT + k];
  if (m.skip) return;
  int ch = m.ye - m.ys, cw = m.xe - m.xs;
  if (ch > SH) ch = SH;
  if (cw > SW) cw = SW;
  int idx = blockIdx.x * 256 + threadIdx.x;
  int x = idx % SW, y = idx / SW;
  if (y >= ch || x >= cw) return;

  float sy = (float)y - m.dyp;
  float sx = (float)x - m.dxp;
  float x0f = floorf(sx), y0f = floorf(sy);
  float wx = sx - x0f, wy = sy - y0f;
  int x0 = (int)x0f, y0 = (int)y0f;
  const float* bl = blurred + (size_t)i * SLOT;

  float v00 = (y0 >= 0 && y0 < ch && x0 >= 0 && x0 < cw) ? bl[y0 * SW + x0] : 0.f;
  float v01 = (y0 >= 0 && y0 < ch && x0 + 1 >= 0 && x0 + 1 < cw) ? bl[y0 * SW + x0 + 1] : 0.f;
  float v10 = (y0 + 1 >= 0 && y0 + 1 < ch && x0 >= 0 && x0 < cw) ? bl[(y0 + 1) * SW + x0] : 0.f;
  float v11 = (y0 + 1 >= 0 && y0 + 1 < ch && x0 + 1 >= 0 && x0 + 1 < cw) ? bl[(y0 + 1) * SW + x0 + 1] : 0.f;

  float v = (1.f - wy) * ((1.f - wx) * v00 + wx * v01) + wy * ((1.f - wx) * v10 + wx * v11);

  size_t o = ((size_t)i * IMG_H + (m.ys + y)) * IMG_W + (m.xs + x);
  sg[o] = v;
  if (v > 0.f) sl[o] = (float)(k + 1);
}

extern "C" void kernel_launch(void* const* d_in, const int* in_sizes, int n_in,
                              void* d_out, int out_size, void* d_ws, size_t ws_size,
                              hipStream_t stream) {
  const float* alpha = (const float*)d_in[0];
  // d_in[1] (font_size_pred) is unused by the reference
  const float* sigp = (const float*)d_in[2];
  const float* tnhp = (const float*)d_in[3];
  const int* ta = (const int*)d_in[4];
  float* out = (float*)d_out;

  char* ws = (char*)d_ws;
  RegionMeta* meta = (RegionMeta*)ws;
  float* g3 = (float*)(ws + 4096);

  float* sg = out;
  float* sl = out + (size_t)4 * IMG_H * IMG_W;

  const size_t slotBytes = (size_t)SLOT * 4;
  const size_t needPar = 65536 + 2 * 32 * slotBytes;   // ~42.4 MB
  const int hBlocks = (SH + HROWS - 1) / HROWS;        // 55
  const int vyBlocks = (SH + 15) / 16;                 // 17

  meta_kernel<<<32, 64, 0, stream>>>(sigp, tnhp, ta, g3, meta);

  if (ws_size >= needPar) {
    // fully parallel across all 32 regions; ordering resolved in composite
    float* tmpH = (float*)(ws + 65536);
    float* blurred = (float*)(ws + 65536 + 32 * slotBytes);
    hpass_kernel<<<dim3(hBlocks, 32), 192, 0, stream>>>(alpha, meta, g3, tmpH, -1);
    vpass_kernel<<<dim3(3, vyBlocks, 32), 256, 0, stream>>>(meta, g3, tmpH, blurred, -1);
    composite_kernel<<<(4 * IMG_H * IMG_W) / 256, 256, 0, stream>>>(meta, blurred, sg, sl);
  } else {
    // fallback: sequential over k (4 regions in parallel), explicit write ordering
    float* tmpH = (float*)(ws + 65536);
    float* blurred = (float*)(ws + 65536 + 4 * slotBytes);
    hipMemsetAsync(d_out, 0, (size_t)out_size * sizeof(float), stream);
    const int blocksPerRegion = (SH * SW) / 256;
    for (int k = 0; k < K_CNT; ++k) {
      hpass_kernel<<<dim3(hBlocks, 4), 192, 0, stream>>>(alpha, meta, g3, tmpH, k);
      vpass_kernel<<<dim3(3, vyBlocks, 4), 256, 0, stream>>>(meta, g3, tmpH, blurred, k);
      shift_kernel<<<dim3(blocksPerRegion, 4), 256, 0, stream>>>(meta, blurred, sg, sl, k);
    }
  }
}